// Round 1
// 273.752 us; speedup vs baseline: 1.2094x; 1.2094x over previous
//
#include <hip/hip_runtime.h>
#include <math.h>

// SparseMoEALU via MFMA: bucket 16384 rows by opcode, then one 4-wave block
// per 4 same-op rows (M=32). Waves cooperate on the tile: GEMM N-dim split
// across the 4 waves, X state fp32 in shared LDS, FFN/attention as bf16 MFMA
// GEMMs with fp32 accumulate; weights pre-transposed to bf16 [N][K] in ws.

typedef __bf16 bfrag __attribute__((ext_vector_type(8)));
typedef float f32x4 __attribute__((ext_vector_type(4)));

#define MFMA16(a,b,c) __builtin_amdgcn_mfma_f32_16x16x32_bf16((a),(b),(c),0,0,0)

constexpr int NB = 16384, NOPS = 37, OP_START = 16;

// ws layout (int32 units for the bucketing region)
constexpr int WS_OPARR  = 0;        // 16384 ints; reused as tileArr after k_scatter
constexpr int WS_CNT    = 16384;
constexpr int WS_OFF    = 16448;    // 38 ints
constexpr int WS_CUR    = 16512;    // 37 ints
constexpr int WS_TB     = 16560;    // 38 ints (tile-base prefix)
constexpr int WS_ROWIDX = 16640;
constexpr int WS_INTS   = 33024;    // -> weight region at byte 132096

// bf16 element offsets inside weight region
constexpr int OFF_QKVT = 0;        // [192][64]
constexpr int OFF_WI1T = 12288;    // 37 x [128][64]
constexpr int OFF_WI2T = 315392;   // 37 x [64][128]
constexpr int OFF_WC1T = 618496;
constexpr int OFF_WC2T = 921600;
constexpr int OFF_WF1T = 1224704;
constexpr int OFF_WF2T = 1527808;
constexpr int OFF_WD1T = 1830912;  // 16 x [128][64]
constexpr int OFF_WD2T = 1961984;  // 16 x [64][128]
constexpr int OFF_WM1T = 2093056;
constexpr int OFF_WM2T = 2224128;

// ---------------- prep kernels ----------------

__global__ void k_zero(int* cnt, int* cur) {
    int t = threadIdx.x;
    if (t < NOPS) { cnt[t] = 0; cur[t] = 0; }
}

__global__ void k_op(const float* __restrict__ x, int* __restrict__ opArr, int* __restrict__ cnt) {
    int b = blockIdx.x * 64 + threadIdx.x;
    const float4* p = (const float4*)(x + (size_t)b * 512 + OP_START);
    float best = -1e30f; int op = 0;
    #pragma unroll
    for (int j = 0; j < 9; ++j) {
        float4 v = p[j];
        int k = j * 4;
        if (v.x > best) { best = v.x; op = k; }
        if (v.y > best) { best = v.y; op = k + 1; }
        if (v.z > best) { best = v.z; op = k + 2; }
        if (v.w > best) { best = v.w; op = k + 3; }
    }
    float last = x[(size_t)b * 512 + OP_START + 36];
    if (last > best) op = 36;
    opArr[b] = op;
    atomicAdd(&cnt[op], 1);
}

__global__ void k_scan(const int* __restrict__ cnt, int* __restrict__ off, int* __restrict__ tb) {
    if (threadIdx.x == 0) {
        int a = 0, t = 0;
        for (int o = 0; o < NOPS; ++o) {
            off[o] = a; a += cnt[o];
            tb[o] = t;  t += (cnt[o] + 3) >> 2;
        }
        off[NOPS] = a; tb[NOPS] = t;
    }
}

// per-block LDS histogram -> 37 global atomics per block (kills the 443-deep
// per-address serialization of 16384 value-returning atomics)
__global__ void k_scatter(const int* __restrict__ opArr, const int* __restrict__ off,
                          int* __restrict__ cur, int* __restrict__ rowIdx) {
    __shared__ int h[NOPS], bb[NOPS];
    int tid = threadIdx.x;
    if (tid < NOPS) h[tid] = 0;
    __syncthreads();
    int b = blockIdx.x * 256 + tid;
    int op = opArr[b];
    int my = atomicAdd(&h[op], 1);
    __syncthreads();
    if (tid < NOPS && h[tid] > 0) bb[tid] = atomicAdd(&cur[tid], h[tid]);
    __syncthreads();
    rowIdx[off[op] + bb[op] + my] = b;
}

// tileArr[g] = (op<<12)|tile — removes the 37-load serial search per block.
// Runs after k_scatter (tileArr aliases opArr; stream order protects).
__global__ void k_tilemap(const int* __restrict__ cnt, const int* __restrict__ tb,
                          int* __restrict__ tileArr) {
    int o = blockIdx.x;
    int n = (cnt[o] + 3) >> 2, base = tb[o];
    for (int t = threadIdx.x; t < n; t += 64)
        tileArr[base + t] = (o << 12) | t;
}

// transpose one [R][C] fp32 matrix -> [C][R] bf16 (289 blocks)
__global__ void k_wt(const float* __restrict__ Wi1, const float* __restrict__ Wi2,
                     const float* __restrict__ Wq,  const float* __restrict__ Wk,
                     const float* __restrict__ Wv,
                     const float* __restrict__ Wc1, const float* __restrict__ Wc2,
                     const float* __restrict__ Wd1, const float* __restrict__ Wd2,
                     const float* __restrict__ Wm1, const float* __restrict__ Wm2,
                     const float* __restrict__ Wf1, const float* __restrict__ Wf2,
                     __bf16* __restrict__ wb) {
    __shared__ float t[8320];  // max R*(C+1) = 128*65
    int m = blockIdx.x;
    const float* src; __bf16* dst; int R, C;
    if      (m < 37)  { src = Wi1 + m * 8192;        dst = wb + OFF_WI1T + m * 8192;        R = 64;  C = 128; }
    else if (m < 74)  { src = Wi2 + (m-37) * 8192;   dst = wb + OFF_WI2T + (m-37) * 8192;   R = 128; C = 64;  }
    else if (m < 111) { src = Wc1 + (m-74) * 8192;   dst = wb + OFF_WC1T + (m-74) * 8192;   R = 64;  C = 128; }
    else if (m < 148) { src = Wc2 + (m-111) * 8192;  dst = wb + OFF_WC2T + (m-111) * 8192;  R = 128; C = 64;  }
    else if (m < 185) { src = Wf1 + (m-148) * 8192;  dst = wb + OFF_WF1T + (m-148) * 8192;  R = 64;  C = 128; }
    else if (m < 222) { src = Wf2 + (m-185) * 8192;  dst = wb + OFF_WF2T + (m-185) * 8192;  R = 128; C = 64;  }
    else if (m < 238) { src = Wd1 + (m-222) * 8192;  dst = wb + OFF_WD1T + (m-222) * 8192;  R = 64;  C = 128; }
    else if (m < 254) { src = Wd2 + (m-238) * 8192;  dst = wb + OFF_WD2T + (m-238) * 8192;  R = 128; C = 64;  }
    else if (m < 270) { src = Wm1 + (m-254) * 8192;  dst = wb + OFF_WM1T + (m-254) * 8192;  R = 64;  C = 128; }
    else if (m < 286) { src = Wm2 + (m-270) * 8192;  dst = wb + OFF_WM2T + (m-270) * 8192;  R = 128; C = 64;  }
    else { const float* q3[3] = {Wq, Wk, Wv}; src = q3[m-286]; dst = wb + OFF_QKVT + (m-286) * 4096; R = 64; C = 64; }
    int n = R * C, Cp = C + 1;
    int logC = (C == 128) ? 7 : 6, logR = (R == 128) ? 7 : 6;
    for (int i = threadIdx.x; i < n; i += 256)
        t[(i >> logC) * Cp + (i & (C - 1))] = src[i];
    __syncthreads();
    for (int o = threadIdx.x; o < n; o += 256) {
        int c = o >> logR, r = o & (R - 1);
        dst[o] = (__bf16)t[r * Cp + c];
    }
}

// ---------------- main kernel helpers ----------------

__device__ __forceinline__ bfrag cvt8(const float* p) {
    float4 a = *(const float4*)p;
    float4 b = *(const float4*)(p + 4);
    bfrag r;
    r[0] = (__bf16)a.x; r[1] = (__bf16)a.y; r[2] = (__bf16)a.z; r[3] = (__bf16)a.w;
    r[4] = (__bf16)b.x; r[5] = (__bf16)b.y; r[6] = (__bf16)b.z; r[7] = (__bf16)b.w;
    return r;
}

__device__ __forceinline__ bfrag zfrag() {
    bfrag r;
    #pragma unroll
    for (int j = 0; j < 8; ++j) r[j] = (__bf16)0.0f;
    return r;
}

// Cooperative FFN: 4 waves on one 32-row tile.
// GEMM1 (M32 N128 K64): wave w owns N-tiles {2w, 2w+1}  -> 8 MFMA/wave
// GEMM2 (M32 N64 K128): wave w owns N-tile w, reads all of H from LDS -> 8 MFMA/wave
__device__ __forceinline__ void ffn_coop(float* Xs, __bf16* Hs,
    const __bf16* __restrict__ W1t, const float* __restrict__ b1,
    const __bf16* __restrict__ W2t, const float* __restrict__ b2,
    int w, int lq, int qd) {
    __syncthreads();
    bfrag a[2][2];
    #pragma unroll
    for (int mt = 0; mt < 2; ++mt)
        #pragma unroll
        for (int kf = 0; kf < 2; ++kf)
            a[mt][kf] = cvt8(&Xs[(mt * 16 + lq) * 68 + kf * 32 + qd * 8]);
    #pragma unroll
    for (int nt2 = 0; nt2 < 2; ++nt2) {
        int nt = w * 2 + nt2;
        float bv = b1[nt * 16 + lq];
        f32x4 acc0 = {bv, bv, bv, bv}, acc1 = acc0;
        #pragma unroll
        for (int kf = 0; kf < 2; ++kf) {
            bfrag wv = *(const bfrag*)(W1t + (nt * 16 + lq) * 64 + kf * 32 + qd * 8);
            acc0 = MFMA16(a[0][kf], wv, acc0);
            acc1 = MFMA16(a[1][kf], wv, acc1);
        }
        #pragma unroll
        for (int r = 0; r < 4; ++r) {
            Hs[(qd * 4 + r) * 136 + nt * 16 + lq]      = (__bf16)fmaxf(acc0[r], 0.0f);
            Hs[(16 + qd * 4 + r) * 136 + nt * 16 + lq] = (__bf16)fmaxf(acc1[r], 0.0f);
        }
    }
    __syncthreads();
    bfrag a2[2][4];
    #pragma unroll
    for (int mt = 0; mt < 2; ++mt)
        #pragma unroll
        for (int kf = 0; kf < 4; ++kf)
            a2[mt][kf] = *(const bfrag*)&Hs[(mt * 16 + lq) * 136 + kf * 32 + qd * 8];
    {
        float bv = b2[w * 16 + lq];
        f32x4 acc0 = {bv, bv, bv, bv}, acc1 = acc0;
        #pragma unroll
        for (int kf = 0; kf < 4; ++kf) {
            bfrag wv = *(const bfrag*)(W2t + (w * 16 + lq) * 128 + kf * 32 + qd * 8);
            acc0 = MFMA16(a2[0][kf], wv, acc0);
            acc1 = MFMA16(a2[1][kf], wv, acc1);
        }
        // wave w writes columns w*16+lq only: race-free across waves
        #pragma unroll
        for (int r = 0; r < 4; ++r) {
            Xs[(qd * 4 + r) * 68 + w * 16 + lq]      += acc0[r];
            Xs[(16 + qd * 4 + r) * 68 + w * 16 + lq] += acc1[r];
        }
    }
}

// Cooperative attention: waves {0,1} -> chunk 0 (rows 0..15), {2,3} -> chunk 1.
// Proj: 12 N-tiles split 6/6 within the wave pair. Scores/softmax/PV: one
// 8-row slot per wave (global slot = w).
__device__ __forceinline__ void attn_coop(float* Xs, __bf16* Qb, __bf16* Kb, __bf16* Vt,
    float* Sf, __bf16* Pb, const __bf16* __restrict__ qkvt, int w, int lq, int qd) {
    int c = w >> 1;
    __syncthreads();
    {   // QKV projection for this wave's chunk
        bfrag a[2];
        #pragma unroll
        for (int kf = 0; kf < 2; ++kf)
            a[kf] = cvt8(&Xs[(c * 16 + lq) * 68 + kf * 32 + qd * 8]);
        int nt0 = (w & 1) * 6;
        #pragma unroll
        for (int i = 0; i < 6; ++i) {
            int nt = nt0 + i;
            f32x4 acc = {0.f, 0.f, 0.f, 0.f};
            #pragma unroll
            for (int kf = 0; kf < 2; ++kf) {
                bfrag wv = *(const bfrag*)(qkvt + (nt * 16 + lq) * 64 + kf * 32 + qd * 8);
                acc = MFMA16(a[kf], wv, acc);
            }
            if (nt < 4) {
                #pragma unroll
                for (int r = 0; r < 4; ++r)
                    Qb[c * 1728 + (qd * 4 + r) * 72 + nt * 16 + lq] = (__bf16)acc[r];
            } else if (nt < 8) {
                #pragma unroll
                for (int r = 0; r < 4; ++r)
                    Kb[c * 1728 + (qd * 4 + r) * 72 + (nt - 4) * 16 + lq] = (__bf16)acc[r];
            } else {
                #pragma unroll
                for (int r = 0; r < 4; ++r) {
                    int m = qd * 4 + r;
                    Vt[((c * 2 + (m >> 3)) * 64 + (nt - 8) * 16 + lq) * 8 + (m & 7)] = (__bf16)acc[r];
                }
            }
        }
    }
    __syncthreads();
    {   // scores S = Q K^T * 1/8 for slot w (chunk c, half sl)
        int sl = w & 1;
        f32x4 acc = {0.f, 0.f, 0.f, 0.f};
        #pragma unroll
        for (int kf = 0; kf < 2; ++kf) {
            bfrag qa = *(const bfrag*)&Qb[c * 1728 + (sl * 8 + lq) * 72 + kf * 32 + qd * 8];
            bfrag kb = *(const bfrag*)&Kb[c * 1728 + (sl * 8 + lq) * 72 + kf * 32 + qd * 8];
            acc = MFMA16(qa, kb, acc);
        }
        if (qd < 2 && lq < 8) {
            #pragma unroll
            for (int r = 0; r < 4; ++r)
                Sf[(w * 8 + qd * 4 + r) * 8 + lq] = acc[r] * 0.125f;
        }
    }
    __syncthreads();
    {   // softmax: wave w handles its slot; lanes 0..7 real rows, 8..15 zero-pad
        int lane = qd * 16 + lq;
        if (lane < 8) {
            const float* sp = &Sf[(w * 8 + lane) * 8];
            float t[8];
            #pragma unroll
            for (int j = 0; j < 8; ++j) t[j] = sp[j];
            float mx = t[0];
            #pragma unroll
            for (int j = 1; j < 8; ++j) mx = fmaxf(mx, t[j]);
            float sum = 0.f;
            #pragma unroll
            for (int j = 0; j < 8; ++j) { t[j] = __expf(t[j] - mx); sum += t[j]; }
            float inv = 1.0f / sum;
            bfrag pv;
            #pragma unroll
            for (int j = 0; j < 8; ++j) pv[j] = (__bf16)(t[j] * inv);
            *(bfrag*)&Pb[(w * 16 + lane) * 8] = pv;
        } else if (lane < 16) {
            *(bfrag*)&Pb[(w * 16 + lane) * 8] = zfrag();
        }
    }
    __syncthreads();
    {   // out += P @ V for slot w (rows w*8 .. w*8+7): race-free across waves
        bfrag pa = zfrag();
        if (qd == 0) pa = *(const bfrag*)&Pb[(w * 16 + lq) * 8];
        #pragma unroll
        for (int nt = 0; nt < 4; ++nt) {
            bfrag vb = zfrag();
            if (qd == 0) vb = *(const bfrag*)&Vt[(w * 64 + nt * 16 + lq) * 8];
            f32x4 acc = {0.f, 0.f, 0.f, 0.f};
            acc = MFMA16(pa, vb, acc);
            if (qd < 2) {
                #pragma unroll
                for (int r = 0; r < 4; ++r)
                    Xs[(w * 8 + qd * 4 + r) * 68 + nt * 16 + lq] += acc[r];
            }
        }
    }
}

// ---------------- main kernel ----------------

__global__ void __launch_bounds__(256, 4)
moe_main(const float* __restrict__ x, float* __restrict__ out,
         const int* __restrict__ tileArr, const int* __restrict__ tb,
         const int* __restrict__ cnt, const int* __restrict__ off,
         const int* __restrict__ rowIdx, const __bf16* __restrict__ wb,
         const float* __restrict__ bi1, const float* __restrict__ bi2,
         const float* __restrict__ bc1, const float* __restrict__ bc2,
         const float* __restrict__ bd1, const float* __restrict__ bd2,
         const float* __restrict__ bm1, const float* __restrict__ bm2,
         const float* __restrict__ bf1_, const float* __restrict__ bf2_) {
    __shared__ float Xs[32 * 68];                  // 8704 B, stride 68 kills bank conflicts
    __shared__ __align__(16) unsigned char UB[19968];
    __bf16* Hs = (__bf16*)UB;                      // [32][136] (FFN phase, overlaps attn bufs)
    __bf16* Qb = (__bf16*)UB;                      // [2][24][72] (attn) = 6912 B
    __bf16* Kb = (__bf16*)(UB + 6912);             // [2][24][72] = 6912 B
    __bf16* Vt = (__bf16*)(UB + 13824);            // [4][64][8]  = 4096 B
    float*  Sf = (float*)(UB + 17920);             // [32][8] f32 = 1024 B
    __bf16* Pb = (__bf16*)(UB + 18944);            // [4][16][8]  = 1024 B

    int g = blockIdx.x;
    if (g >= tb[NOPS]) return;
    int v = tileArr[g];
    int op = v >> 12, tile = v & 4095;

    int tid = threadIdx.x;
    int w = tid >> 6, lane = tid & 63, lq = lane & 15, qd = lane >> 4;

    int base = off[op] + tile * 4;
    int nr = cnt[op] - tile * 4; if (nr > 4) nr = 4;
    int rows[4];
    #pragma unroll
    for (int s = 0; s < 4; ++s) rows[s] = rowIdx[base + (s < nr ? s : nr - 1)];

    // load X (4 rows x 8 pos x 64 ch)
    for (int i = tid; i < 2048; i += 256) {
        int m = i >> 6, d = i & 63;
        Xs[m * 68 + d] = x[(size_t)rows[m >> 3] * 512 + (m & 7) * 64 + d];
    }
    // (ffn_coop opens with __syncthreads)

    // Stage 1: initial experts
    ffn_coop(Xs, Hs, wb + OFF_WI1T + op * 8192, bi1 + op * 128,
                     wb + OFF_WI2T + op * 8192, bi2 + op * 64, w, lq, qd);

    // Stages 2-3: carry cascade
    bool carry = (op <= 2) || (op >= 10 && op <= 13);
    if (carry) {
        const __bf16* qkvt = wb + OFF_QKVT;
        for (int it = 0; it < 7; ++it) {
            attn_coop(Xs, Qb, Kb, Vt, Sf, Pb, qkvt, w, lq, qd);
            ffn_coop(Xs, Hs, wb + OFF_WC1T + op * 8192, bc1 + op * 128,
                             wb + OFF_WC2T + op * 8192, bc2 + op * 64, w, lq, qd);
        }
    }
    // DIV / MOD iterative FFNs
    if (op == 3) {
        for (int i = 0; i < 16; ++i)
            ffn_coop(Xs, Hs, wb + OFF_WD1T + i * 8192, bd1 + i * 128,
                             wb + OFF_WD2T + i * 8192, bd2 + i * 64, w, lq, qd);
    }
    if (op == 4) {
        for (int i = 0; i < 16; ++i)
            ffn_coop(Xs, Hs, wb + OFF_WM1T + i * 8192, bm1 + i * 128,
                             wb + OFF_WM2T + i * 8192, bm2 + i * 64, w, lq, qd);
    }
    // Stage 4: final experts
    ffn_coop(Xs, Hs, wb + OFF_WF1T + op * 8192, bf1_ + op * 128,
                     wb + OFF_WF2T + op * 8192, bf2_ + op * 64, w, lq, qd);

    __syncthreads();
    for (int i = tid; i < nr * 512; i += 256) {
        int s = i >> 9, rem = i & 511;
        out[(size_t)rows[s] * 512 + rem] = Xs[(s * 8 + (rem >> 6)) * 68 + (rem & 63)];
    }
}

// ---------------- launch ----------------

extern "C" void kernel_launch(void* const* d_in, const int* in_sizes, int n_in,
                              void* d_out, int out_size, void* d_ws, size_t ws_size,
                              hipStream_t stream) {
    (void)in_sizes; (void)n_in; (void)out_size; (void)ws_size;
    const float* x   = (const float*)d_in[0];
    const float* Wi1 = (const float*)d_in[1];
    const float* bi1 = (const float*)d_in[2];
    const float* Wi2 = (const float*)d_in[3];
    const float* bi2 = (const float*)d_in[4];
    const float* Wq  = (const float*)d_in[5];
    const float* Wk  = (const float*)d_in[6];
    const float* Wv  = (const float*)d_in[7];
    const float* Wc1 = (const float*)d_in[8];
    const float* bc1 = (const float*)d_in[9];
    const float* Wc2 = (const float*)d_in[10];
    const float* bc2 = (const float*)d_in[11];
    const float* Wd1 = (const float*)d_in[12];
    const float* bd1 = (const float*)d_in[13];
    const float* Wd2 = (const float*)d_in[14];
    const float* bd2 = (const float*)d_in[15];
    const float* Wm1 = (const float*)d_in[16];
    const float* bm1 = (const float*)d_in[17];
    const float* Wm2 = (const float*)d_in[18];
    const float* bm2 = (const float*)d_in[19];
    const float* Wf1 = (const float*)d_in[20];
    const float* bf1 = (const float*)d_in[21];
    const float* Wf2 = (const float*)d_in[22];
    const float* bf2 = (const float*)d_in[23];
    float* out = (float*)d_out;

    int* wsi     = (int*)d_ws;
    int* opArr   = wsi + WS_OPARR;
    int* tileArr = wsi + WS_OPARR;   // alias: safe, written after k_scatter consumes opArr
    int* cnt     = wsi + WS_CNT;
    int* off     = wsi + WS_OFF;
    int* cur     = wsi + WS_CUR;
    int* tb      = wsi + WS_TB;
    int* rowIdx  = wsi + WS_ROWIDX;
    __bf16* wb   = (__bf16*)((char*)d_ws + WS_INTS * 4);

    k_zero<<<1, 64, 0, stream>>>(cnt, cur);
    k_op<<<NB / 64, 64, 0, stream>>>(x, opArr, cnt);
    k_scan<<<1, 64, 0, stream>>>(cnt, off, tb);
    k_scatter<<<NB / 256, 256, 0, stream>>>(opArr, off, cur, rowIdx);
    k_tilemap<<<NOPS, 64, 0, stream>>>(cnt, tb, tileArr);
    k_wt<<<289, 256, 0, stream>>>(Wi1, Wi2, Wq, Wk, Wv, Wc1, Wc2, Wd1, Wd2, Wm1, Wm2, Wf1, Wf2, wb);
    moe_main<<<NB / 4 + NOPS, 256, 0, stream>>>(x, out, tileArr, tb, cnt, off, rowIdx, wb,
                                                bi1, bi2, bc1, bc2, bd1, bd2, bm1, bm2, bf1, bf2);
}